// Round 11
// baseline (554.162 us; speedup 1.0000x reference)
//
#include <hip/hip_runtime.h>
#include <math.h>
#include <stdint.h>

#define S_LEN 2048
#define D_DIM 4096
#define NHEAD 32
#define HDIM  128

typedef int      v4i __attribute__((ext_vector_type(4)));
typedef float    v4f __attribute__((ext_vector_type(4)));
typedef _Float16 v8h __attribute__((ext_vector_type(8)));

__device__ __forceinline__ float quant128(float x) {
  return fminf(fmaxf(rintf(x / 0.1f), -128.f), 127.f);
}
// async 16B global->LDS DMA; LDS side is wave-uniform base + lane*16
__device__ __forceinline__ void gl_lds16(const void* g, void* l) {
  __builtin_amdgcn_global_load_lds(
      (const __attribute__((address_space(1))) void*)g,
      (__attribute__((address_space(3))) void*)l, 16, 0, 0);
}

// ---------------- prep kernels ----------------
__global__ __launch_bounds__(256) void quant_hidden_k(const float* __restrict__ in,
                                                      int8_t* __restrict__ out) {
  const int idx = blockIdx.x * 256 + threadIdx.x;
  const float4 v = ((const float4*)in)[idx];
  const int q0 = (int)quant128(v.x), q1 = (int)quant128(v.y);
  const int q2 = (int)quant128(v.z), q3 = (int)quant128(v.w);
  ((int*)out)[idx] = (q0 & 0xff) | ((q1 & 0xff) << 8) | ((q2 & 0xff) << 16) | ((q3 & 0xff) << 24);
}

// fused f32->int8 convert of wq,wk,wv into one contiguous 48MB dst
__global__ __launch_bounds__(256) void wconv3_k(const float* __restrict__ a,
                                                const float* __restrict__ b,
                                                const float* __restrict__ c,
                                                int8_t* __restrict__ out) {
  const int which = blockIdx.x >> 14;
  const int sub = blockIdx.x & 16383;
  const float* src = (which == 0) ? a : (which == 1) ? b : c;
  const int idx = sub * 256 + threadIdx.x;
  const float4 v = ((const float4*)src)[idx];  // int4-valued floats, exact
  const int q0 = __float2int_rn(v.x), q1 = __float2int_rn(v.y);
  const int q2 = __float2int_rn(v.z), q3 = __float2int_rn(v.w);
  ((int*)out)[(size_t)which * 4194304 + idx] =
      (q0 & 0xff) | ((q1 & 0xff) << 8) | ((q2 & 0xff) << 16) | ((q3 & 0xff) << 24);
}

__global__ __launch_bounds__(256) void wconv_k(const float* __restrict__ in,
                                               int8_t* __restrict__ out) {
  const int idx = blockIdx.x * 256 + threadIdx.x;
  const float4 v = ((const float4*)in)[idx];
  const int q0 = __float2int_rn(v.x), q1 = __float2int_rn(v.y);
  const int q2 = __float2int_rn(v.z), q3 = __float2int_rn(v.w);
  ((int*)out)[idx] = (q0 & 0xff) | ((q1 & 0xff) << 8) | ((q2 & 0xff) << 16) | ((q3 & 0xff) << 24);
}

__global__ __launch_bounds__(256) void rope_tab_k(const int* __restrict__ pos,
                                                  float* __restrict__ ct,
                                                  float* __restrict__ st) {
  const int idx = blockIdx.x * 256 + threadIdx.x;  // [S][64]
  const int s = idx >> 6, j = idx & 63;
  const float inv = exp2f((float)j * -0.20762050593046016f);  // 10000^(-j/64)
  const float a = (float)pos[s] * inv;
  float si, c;
  sincosf(a, &si, &c);
  ct[idx] = c;
  st[idx] = si;
}

// ---------------------------------------------------------------------------
// int8 MFMA GEMM v10 — m201-style 8-phase interleave.
// Across R5-R10: scheduling null, geometry regress, 2x occupancy null —
// MfmaUtil pinned ~37% = the documented 2-barrier-structure ceiling. The
// measured fix (m196/m198: +28-41% with NO swizzle change) is the fine
// phase interleave: split each K-tile into phases of {ds_read subtile ||
// 2 stage ops -> barrier -> lgkmcnt(0) -> 16-MFMA cluster -> barrier},
// with vmcnt counted ONCE per tile (never 0 mid-loop).
// Geometry: 256x256 tile, BK=64, 8 waves (2m x 4n), per-wave 128x64,
// 32 MFMA/tile/wave = 2 phases x 16 (same 8-MFMA-per-barrier density as
// m201). LDS: 3 bufs x (A 16KB + B 16KB) = 96 KB. Stage: 4 units/tile
// (1 gl_lds/thread each: A-half, A-half, B-half, B-half), 2 issued per
// phase, targeting tile kt+2 (buf = that of tile kt-1, whose last readers
// finished >=2 barriers earlier — race-free).
// vmcnt ledger: at end of tile kt (phase B), wait vmcnt(4) [set kt+2 = 4
// newer ops] proving set kt+1 retired; tail: vmcnt(0). Reads of a tile only
// after that wait + barrier. Swizzle/frag offsets/epilogue verbatim R9
// (harness-verified, 0 bank conflicts).
// ---------------------------------------------------------------------------
template <int MODE>
__device__ __forceinline__ void gemm_body(
    int8_t* __restrict__ LS, const int8_t* __restrict__ A8,
    const int8_t* __restrict__ W8, const float* __restrict__ s0,
    const float* __restrict__ s1, const float* __restrict__ s2,
    const float* __restrict__ ctab, const float* __restrict__ stab,
    void* __restrict__ out0, void* __restrict__ out1, void* __restrict__ out2,
    int nwg) {
  int8_t* const Abase = LS;            // 3 x 16KB (256 rows x 64B)
  int8_t* const Bbase = LS + 49152;    // 3 x 16KB (256 rows x 64B)

  const int t = threadIdx.x;
  const int w = t >> 6, lane = t & 63, g = lane >> 4, l15 = lane & 15;
  const int wm = w >> 2, wn = w & 3;  // 2m x 4n wave grid; wave tile 128x64

  // XCD-contiguous logical id + 4x4 tile-group swizzle (8 m-tiles: MG=2)
  const int bid = blockIdx.x;
  const int lb = (bid & 7) * (nwg >> 3) + (bid >> 3);
  const int within = lb & 15, g16 = lb >> 4;
  const int bm = ((g16 & 1) * 4 + (within >> 2)) * 256;
  const int bn = ((g16 >> 1) * 4 + (within & 3)) * 256;

  // ---- staging: unit u covers 128 rows (8KB = 1 gl_lds/thread).
  // thread t -> row128 = t>>2, chunk = t&3; source chunk swizzled so LDS
  // slot c of row r holds source chunk c ^ ((r>>1)&3) (R9-verified).
  const int srow = t >> 2;  // 0..127 within unit
  const int sc16 = ((t & 3) ^ ((srow >> 1) & 3)) * 16;
  const int sdst = t * 16;  // linear dest within unit
  const int8_t* srcA[2];
  const int8_t* srcB[2];
#pragma unroll
  for (int u = 0; u < 2; ++u) {
    srcA[u] = A8 + (size_t)(bm + u * 128 + srow) * D_DIM + sc16;
    srcB[u] = W8 + (size_t)(bn + u * 128 + srow) * D_DIM + sc16;
  }

  // STAGE_UNIT: U in {0,1} = A halves; {2,3} = B halves. BUF = 0..2.
#define STAGE_UNIT(KT, BUF, U)                                              \
  {                                                                         \
    const int kof_ = (KT) * 64;                                             \
    if ((U) < 2)                                                            \
      gl_lds16(srcA[(U)] + kof_, Abase + (BUF) * 16384 + (U) * 8192 + sdst);\
    else                                                                    \
      gl_lds16(srcB[(U) - 2] + kof_,                                        \
               Bbase + (BUF) * 16384 + ((U) - 2) * 8192 + sdst);            \
  }

  // frag byte offsets; chunk = g ^ ((l15>>1)&3) (R9-verified, 0 conflicts)
  const int cg = ((g ^ ((l15 >> 1) & 3)) << 4);
  const int nc0 = (wn & 1) * 32 + (wn >> 1) * 128;  // RoPE-pair column base
  int aoffs[8], boffs[4];
#pragma unroll
  for (int mi = 0; mi < 8; ++mi)
    aoffs[mi] = (wm * 128 + mi * 16 + l15) * 64 + cg;
#pragma unroll
  for (int ni = 0; ni < 4; ++ni)
    boffs[ni] = (nc0 + (ni & 1) * 16 + (ni >> 1) * 64 + l15) * 64 + cg;

  v4i acc[8][4];
#pragma unroll
  for (int mi = 0; mi < 8; ++mi)
#pragma unroll
    for (int ni = 0; ni < 4; ++ni) acc[mi][ni] = (v4i){0, 0, 0, 0};

  // prologue: stage tiles 0,1; prove set0 retired (4 newer ops = set1)
#pragma unroll
  for (int u = 0; u < 4; ++u) STAGE_UNIT(0, 0, u)
#pragma unroll
  for (int u = 0; u < 4; ++u) STAGE_UNIT(1, 1, u)
  asm volatile("s_waitcnt vmcnt(4)" ::: "memory");
  __builtin_amdgcn_s_barrier();
  __builtin_amdgcn_sched_barrier(0);

  v4i af[4], bf[4];
  int bi = 0;
  for (int kt = 0; kt < 64; ++kt) {
    const int bs = (bi >= 1) ? bi - 1 : 2;  // buf of tile kt+2
    // ---- phase A: bf[0..3] + af(mi0..3) reads || stage units 0,1 ----
    {
      const int8_t* Ab_ = Abase + bi * 16384;
      const int8_t* Bb_ = Bbase + bi * 16384;
#pragma unroll
      for (int ni = 0; ni < 4; ++ni) bf[ni] = *(const v4i*)(Bb_ + boffs[ni]);
#pragma unroll
      for (int mi = 0; mi < 4; ++mi) af[mi] = *(const v4i*)(Ab_ + aoffs[mi]);
    }
    if (kt + 2 < 64) {
      STAGE_UNIT(kt + 2, bs, 0)
      STAGE_UNIT(kt + 2, bs, 1)
    }
    __builtin_amdgcn_s_barrier();
    asm volatile("s_waitcnt lgkmcnt(0)" ::: "memory");
    __builtin_amdgcn_sched_barrier(0);
    __builtin_amdgcn_s_setprio(1);
#pragma unroll
    for (int mi = 0; mi < 4; ++mi)
#pragma unroll
      for (int ni = 0; ni < 4; ++ni)
        acc[mi][ni] = __builtin_amdgcn_mfma_i32_16x16x64_i8(
            af[mi], bf[ni], acc[mi][ni], 0, 0, 0);
    __builtin_amdgcn_s_setprio(0);
    __builtin_amdgcn_s_barrier();
    __builtin_amdgcn_sched_barrier(0);

    // ---- phase B: af(mi4..7) reads || stage units 2,3 ----
    {
      const int8_t* Ab_ = Abase + bi * 16384;
#pragma unroll
      for (int mi = 0; mi < 4; ++mi)
        af[mi] = *(const v4i*)(Ab_ + aoffs[4 + mi]);
    }
    if (kt + 2 < 64) {
      STAGE_UNIT(kt + 2, bs, 2)
      STAGE_UNIT(kt + 2, bs, 3)
    }
    __builtin_amdgcn_s_barrier();
    asm volatile("s_waitcnt lgkmcnt(0)" ::: "memory");
    __builtin_amdgcn_sched_barrier(0);
    __builtin_amdgcn_s_setprio(1);
#pragma unroll
    for (int mi = 0; mi < 4; ++mi)
#pragma unroll
      for (int ni = 0; ni < 4; ++ni)
        acc[4 + mi][ni] = __builtin_amdgcn_mfma_i32_16x16x64_i8(
            af[mi], bf[ni], acc[4 + mi][ni], 0, 0, 0);
    __builtin_amdgcn_s_setprio(0);
    // tile boundary: prove set kt+1 retired (newer = set kt+2 if issued)
    if (kt + 1 < 64) {
      if (kt + 2 < 64)
        asm volatile("s_waitcnt vmcnt(4)" ::: "memory");
      else
        asm volatile("s_waitcnt vmcnt(0)" ::: "memory");
    }
    __builtin_amdgcn_s_barrier();
    __builtin_amdgcn_sched_barrier(0);

    bi = (bi == 2) ? 0 : bi + 1;
  }
#undef STAGE_UNIT

  // ---- epilogue (C/D map: row = g*4+r, col = l15 within each 16x16) ----
  const int srow0 = bm + wm * 128;
  if (MODE == 1) {
    float* dst = (float*)out0;
#pragma unroll
    for (int ni = 0; ni < 4; ++ni) {
      const int col = bn + nc0 + (ni & 1) * 16 + (ni >> 1) * 64 + l15;
      const float sc = 0.1f * s0[col];
#pragma unroll
      for (int mi = 0; mi < 8; ++mi)
#pragma unroll
        for (int r = 0; r < 4; ++r)
          dst[(size_t)(srow0 + mi * 16 + g * 4 + r) * D_DIM + col] =
              (float)acc[mi][ni][r] * sc;
    }
  } else {
    const int seg = bn >> 12;        // 0=Q 1=K 2=V (BN=256 < 4096, uniform)
    const int bcol = bn & 4095;
    if (seg == 2) {
      _Float16* dst = (_Float16*)out2;
#pragma unroll
      for (int ni = 0; ni < 4; ++ni) {
        const int col = bcol + nc0 + (ni & 1) * 16 + (ni >> 1) * 64 + l15;
        const float scv = 0.1f * s2[col];
#pragma unroll
        for (int mi = 0; mi < 8; ++mi)
#pragma unroll
          for (int r = 0; r < 4; ++r) {
            const int s = srow0 + mi * 16 + g * 4 + r;
            dst[(size_t)col * S_LEN + s] = (_Float16)quant128((float)acc[mi][ni][r] * scv);
          }
      }
    } else {
      const float* wsc = seg ? s1 : s0;
      int8_t* dst = seg ? (int8_t*)out1 : (int8_t*)out0;
      const int hb = bcol + (wn >> 1) * 128;  // head base column
#pragma unroll
      for (int ni = 0; ni < 2; ++ni) {        // low-d frag; pair is ni+2
        const int dlo = (wn & 1) * 32 + ni * 16 + l15;  // 0..63 within head
        const int clo = hb + dlo;
        const float sc0 = 0.1f * wsc[clo];
        const float sc1 = 0.1f * wsc[clo + 64];
#pragma unroll
        for (int mi = 0; mi < 8; ++mi)
#pragma unroll
          for (int r = 0; r < 4; ++r) {
            const int s = srow0 + mi * 16 + g * 4 + r;
            const float c = ctab[s * 64 + dlo];
            const float si = stab[s * 64 + dlo];
            const float x1 = (float)acc[mi][ni][r] * sc0;
            const float x2 = (float)acc[mi][ni + 2][r] * sc1;
            dst[(size_t)s * D_DIM + clo] = (int8_t)quant128(x1 * c - x2 * si);
            dst[(size_t)s * D_DIM + clo + 64] = (int8_t)quant128(x2 * c + x1 * si);
          }
      }
    }
  }
}

__global__ __launch_bounds__(512) void gemm_qkv(
    const int8_t* __restrict__ A8, const int8_t* __restrict__ W8,
    const float* __restrict__ s0, const float* __restrict__ s1,
    const float* __restrict__ s2, const float* __restrict__ ctab,
    const float* __restrict__ stab, void* __restrict__ out0,
    void* __restrict__ out1, void* __restrict__ out2) {
  __shared__ __align__(16) int8_t LS[6 * 16384];  // 96 KB
  gemm_body<0>(LS, A8, W8, s0, s1, s2, ctab, stab, out0, out1, out2, 384);
}

__global__ __launch_bounds__(512) void gemm_out(
    const int8_t* __restrict__ A8, const int8_t* __restrict__ W8,
    const float* __restrict__ s0, const float* __restrict__ ctab,
    const float* __restrict__ stab, void* __restrict__ out0) {
  __shared__ __align__(16) int8_t LS[6 * 16384];  // 96 KB
  gemm_body<1>(LS, A8, W8, s0, s0, s0, ctab, stab, out0, out0, out0, 128);
}

// ---------------------------------------------------------------------------
// Flash attention v8 (unchanged from R8 — passing, ~89 µs).
// ---------------------------------------------------------------------------
__global__ __launch_bounds__(512, 4) void attn_v8(
    const int8_t* __restrict__ q8, const int8_t* __restrict__ k8,
    const _Float16* __restrict__ vT, int8_t* __restrict__ o8) {
  __shared__ __align__(16) int8_t Kls[3][8192];   // 64 slots x 128 B (d)
  __shared__ __align__(16) int8_t Vls[3][16384];  // 128 d x 128 B (64 keys f16)
  const int jj = 15 - blockIdx.x;      // q-tile group (8 tiles), longest first
  const int h = blockIdx.y;
  const int t = threadIdx.x;
  const int w = t >> 6, lane = t & 63, g = lane >> 4, l15 = lane & 15;
  const int T = 2 * jj + 2;            // shared key-tile count (8 waves)
  const int q0 = (jj * 8 + w) * 16;    // wave-private q-tile
  const int q_lane = q0 + l15;         // this lane's q-row (score column)
  const float SSCALE = 8.838834764831845e-4f;  // 0.01 / sqrt(128)
  const v8h vones = {(_Float16)1, (_Float16)1, (_Float16)1, (_Float16)1,
                     (_Float16)1, (_Float16)1, (_Float16)1, (_Float16)1};

  // --- per-thread DMA descriptors (512 threads: K = 1 instr, V = 2) ---
  const int ks_slot = t >> 3;
  const int ks_cs = (t & 7) ^ (ks_slot & 7);  // XOR bank swizzle via source
  const int ks_key = ((ks_slot >> 5) & 1) * 32 + ((ks_slot >> 3) & 1) * 16 +
                     ((ks_slot >> 2) & 1) * 8 + ((ks_slot >> 4) & 1) * 4 +
                     (ks_slot & 3);  // slot -> key bit permutation (v5-proven)
  const int k_src = ks_key * D_DIM + ks_cs * 16;  // bytes within K tile
  const int k_dst = t * 16;
  int v_src[2], v_dst[2];
#pragma unroll
  for (int i = 0; i < 2; ++i) {
    const int lin = i * 512 + t;
    const int d = lin >> 3;
    const int cs = (lin & 7) ^ (d & 7);
    v_src[i] = d * S_LEN + cs * 8;  // f16 units; V keys in natural order
    v_dst[i] = lin * 16;
  }
  const int8_t* kbg = k8 + (size_t)h * HDIM;
  const _Float16* vbg = vT + (size_t)h * HDIM * S_LEN;

  auto stage = [&](int kt, int b) {
    const int8_t* ks = kbg + (size_t)kt * (64 * D_DIM);
    const _Float16* vs = vbg + kt * 64;
    gl_lds16(ks + k_src, &Kls[b][k_dst]);
#pragma unroll
    for (int i = 0; i < 2; ++i) gl_lds16(vs + v_src[i], &Vls[b][v_dst[i]]);
  };

  // Q fragments (B-operand of swapped QK): rows q0..q0+15
  const v4i qa0 = *(const v4i*)(q8 + (size_t)q_lane * D_DIM + h * HDIM + g * 16);
  const v4i qa1 = *(const v4i*)(q8 + (size_t)q_lane * D_DIM + h * HDIM + 64 + g * 16);

  v4f o[8];
#pragma unroll
  for (int n = 0; n < 8; ++n) o[n] = (v4f){0.f, 0.f, 0.f, 0.f};
  v4f lacc = (v4f){0.f, 0.f, 0.f, 0.f};  // denom per o-row (q = g*4+r)
  float m_i = -INFINITY;                 // running max for q = q_lane

  stage(0, 0);
  if (T > 1) stage(1, 1);

  int bi = 0;
  for (int kt = 0; kt < T; ++kt) {
    if (kt + 1 < T)
      asm volatile("s_waitcnt vmcnt(3)" ::: "memory");  // stage(kt) retired
    else
      asm volatile("s_waitcnt vmcnt(0)" ::: "memory");  // last tile
    __builtin_amdgcn_s_barrier();
    __builtin_amdgcn_sched_barrier(0);  // fence: nothing hoists above barrier
    if (kt + 2 < T) stage(kt + 2, bi >= 1 ? bi - 1 : bi + 2);  // (bi+2)%3

    // ---- scores: swapped int8 MFMA; slot s = nt*16 + g*4 + r, col = q ----
    const int ksw = (l15 & 7);
    float sc[4][4];
#pragma unroll
    for (int nt = 0; nt < 4; ++nt) {
      const int8_t* kr = &Kls[bi][(nt * 16 + l15) * 128];
      const v4i kb0 = *(const v4i*)(kr + ((g ^ ksw) * 16));
      const v4i kb1 = *(const v4i*)(kr + (((4 + g) ^ ksw) * 16));
      v4i c = (v4i){0, 0, 0, 0};
      c = __builtin_amdgcn_mfma_i32_16x16x64_i8(kb0, qa0, c, 0, 0, 0);
      c = __builtin_amdgcn_mfma_i32_16x16x64_i8(kb1, qa1, c, 0, 0, 0);
#pragma unroll
      for (int r = 0; r < 4; ++r) {
        float s = (float)c[r] * SSCALE;
        if (kt >= T - 2) {  // diagonal spans the last TWO tiles (128 q rows)
          const int key = kt * 64 + ((nt >> 1) << 5) + ((g >> 1) << 4) +
                          ((g & 1) << 3) + ((nt & 1) << 2) + r;
          if (key > q_lane) s = -1.0e30f;
        }
        sc[nt][r] = s;
      }
    }
    // ---- online softmax: per-lane column max + 2 shfl_xor across g ----
    float mx = fmaxf(fmaxf(fmaxf(sc[0][0], sc[0][1]), fmaxf(sc[0][2], sc[0][3])),
                     fmaxf(fmaxf(sc[1][0], sc[1][1]), fmaxf(sc[1][2], sc[1][3])));
    mx = fmaxf(mx, fmaxf(fmaxf(fmaxf(sc[2][0], sc[2][1]), fmaxf(sc[2][2], sc[2][3])),
                         fmaxf(fmaxf(sc[3][0], sc[3][1]), fmaxf(sc[3][2], sc[3][3]))));
    mx = fmaxf(mx, __shfl_xor(mx, 16));
    mx = fmaxf(mx, __shfl_xor(mx, 32));
    const float mnew = fmaxf(m_i, mx);
    const float alpha = __expf(m_i - mnew);
    m_i = mnew;

    float p[4][4];
#pragma unroll
    for (int nt = 0; nt < 4; ++nt)
#pragma unroll
      for (int r = 0; r < 4; ++r) p[nt][r] = __expf(sc[nt][r] - m_i);

    // P -> f16 A-frags, purely in-lane (slot permutation absorbed in K rows)
    v8h ph0, ph1;
#pragma unroll
    for (int e = 0; e < 8; ++e) {
      ph0[e] = (_Float16)p[e >> 2][e & 3];
      ph1[e] = (_Float16)p[2 + (e >> 2)][e & 3];
    }
    // alpha for this lane's o-rows (q = g*4+r): fetch from lane l15 = g*4+r
    float a_r[4];
#pragma unroll
    for (int r = 0; r < 4; ++r)
      a_r[r] = __shfl(alpha, (lane & 48) | (g * 4 + r));
#pragma unroll
    for (int n = 0; n < 8; ++n)
#pragma unroll
      for (int r = 0; r < 4; ++r) o[n][r] *= a_r[r];
#pragma unroll
    for (int r = 0; r < 4; ++r) lacc[r] *= a_r[r];

    __builtin_amdgcn_s_setprio(1);
    // denominator rides the MFMA pipe (B = ones); same f16 P as numerator
    lacc = __builtin_amdgcn_mfma_f32_16x16x32_f16(ph0, vones, lacc, 0, 0, 0);
    lacc = __builtin_amdgcn_mfma_f32_16x16x32_f16(ph1, vones, lacc, 0, 0, 0);
    // ---- PV: V from LDS (natural key order), XOR-swizzled b128 reads ----
#pragma unroll
    for (int nt = 0; nt < 8; ++nt) {
      const int8_t* vr = &Vls[bi][(nt * 16 + l15) * 128];
      const v8h v0 = *(const v8h*)(vr + ((g ^ ksw) * 16));
      const v8h v1 = *(const v8h*)(vr + (((4 + g) ^ ksw) * 16));
      o[nt] = __builtin_amdgcn_mfma_f32_16x16x32_f16(ph0, v0, o[nt], 0, 0, 0);
      o[nt] = __builtin_amdgcn_mfma_f32_16x16x32_f16(ph1, v1, o[nt], 0, 0, 0);
    }
    __builtin_amdgcn_s_setprio(0);

    bi = (bi == 2) ? 0 : bi + 1;
  }

  // ---- epilogue: normalize + int8 quantize, wave-private, no barrier ----
#pragma unroll
  for (int r = 0; r < 4; ++r) {
    const float rL = 1.0f / lacc[r];
    const size_t row = (size_t)(q0 + g * 4 + r) * D_DIM + h * HDIM;
#pragma unroll
    for (int nt = 0; nt < 8; ++nt) {
      // out = res*0.1/L; out_q = rint(out/0.1) clamp +-127 (0.1 cancels)
      const int q = (int)fminf(fmaxf(rintf(o[nt][r] * rL), -127.f), 127.f);
      o8[row + nt * 16 + l15] = (int8_t)q;
    }
  }
}

// ---------------------------------------------------------------------------
extern "C" void kernel_launch(void* const* d_in, const int* in_sizes, int n_in,
                              void* d_out, int out_size, void* d_ws, size_t ws_size,
                              hipStream_t stream) {
  (void)in_sizes; (void)n_in; (void)out_size; (void)ws_size;
  const float* hidden = (const float*)d_in[0];
  const float* wq = (const float*)d_in[1];
  const float* wk = (const float*)d_in[2];
  const float* wv = (const float*)d_in[3];
  const float* wo = (const float*)d_in[4];
  const float* sq = (const float*)d_in[5];
  const float* sk = (const float*)d_in[6];
  const float* sv = (const float*)d_in[7];
  const float* so = (const float*)d_in[8];
  // d_in[9] = attention_mask (pure causal; handled analytically)
  const int* pos = (const int*)d_in[10];
  float* out = (float*)d_out;

  char* ws = (char*)d_ws;
  int8_t* h8 = (int8_t*)ws;                                   // 8 MB (later o8)
  int8_t* q8 = (int8_t*)(ws + (8ull << 20));                  // 8 MB
  int8_t* k8 = (int8_t*)(ws + (16ull << 20));                 // 8 MB
  _Float16* vT = (_Float16*)(ws + (24ull << 20));             // 16 MB f16 [D][S]
  int8_t* w8a = (int8_t*)(ws + (40ull << 20));                // 16 MB (wq, later wo)
  int8_t* w8b = (int8_t*)(ws + (56ull << 20));                // 16 MB (wk)
  int8_t* w8c = (int8_t*)(ws + (72ull << 20));                // 16 MB (wv)
  float* ctab = (float*)(ws + (88ull << 20));                 // 512 KB
  float* stab = (float*)(ws + (88ull << 20) + (512ull << 10));
  int8_t* o8 = h8;  // h8 dead after qkv-GEMM; attn writes o8 there

  hipLaunchKernelGGL(rope_tab_k, dim3(512), dim3(256), 0, stream, pos, ctab, stab);
  hipLaunchKernelGGL(quant_hidden_k, dim3(8192), dim3(256), 0, stream, hidden, h8);
  hipLaunchKernelGGL(wconv3_k, dim3(49152), dim3(256), 0, stream, wq, wk, wv, w8a);

  // fused QKV: 8 m-tiles x 48 n-tiles = 384 blocks (256x256 tiles)
  hipLaunchKernelGGL(gemm_qkv, dim3(384), dim3(512), 0, stream, h8, w8a,
                     sq, sk, sv, ctab, stab, (void*)q8, (void*)k8, (void*)vT);
  hipLaunchKernelGGL(wconv_k, dim3(16384), dim3(256), 0, stream, wo, w8a);  // QKV weights dead
  // attn: 16 q-groups x 32 heads, 512 threads (8 waves), 2 blocks/CU
  hipLaunchKernelGGL(attn_v8, dim3(16, 32), dim3(512), 0, stream, q8, k8, vT, o8);
  // out-proj: 8 x 16 = 128 blocks (all resident)
  hipLaunchKernelGGL(gemm_out, dim3(128), dim3(512), 0, stream, o8, w8a,
                     so, ctab, stab, (void*)out);
}

// Round 12
// 487.630 us; speedup vs baseline: 1.1364x; 1.1364x over previous
//
#include <hip/hip_runtime.h>
#include <math.h>
#include <stdint.h>

#define S_LEN 2048
#define D_DIM 4096
#define NHEAD 32
#define HDIM  128

typedef int      v4i __attribute__((ext_vector_type(4)));
typedef float    v4f __attribute__((ext_vector_type(4)));
typedef _Float16 v8h __attribute__((ext_vector_type(8)));

__device__ __forceinline__ float quant128(float x) {
  return fminf(fmaxf(rintf(x / 0.1f), -128.f), 127.f);
}
// async 16B global->LDS DMA; LDS side is wave-uniform base + lane*16
__device__ __forceinline__ void gl_lds16(const void* g, void* l) {
  __builtin_amdgcn_global_load_lds(
      (const __attribute__((address_space(1))) void*)g,
      (__attribute__((address_space(3))) void*)l, 16, 0, 0);
}

// ---------------- prep kernels ----------------
__global__ __launch_bounds__(256) void quant_hidden_k(const float* __restrict__ in,
                                                      int8_t* __restrict__ out) {
  const int idx = blockIdx.x * 256 + threadIdx.x;
  const float4 v = ((const float4*)in)[idx];
  const int q0 = (int)quant128(v.x), q1 = (int)quant128(v.y);
  const int q2 = (int)quant128(v.z), q3 = (int)quant128(v.w);
  ((int*)out)[idx] = (q0 & 0xff) | ((q1 & 0xff) << 8) | ((q2 & 0xff) << 16) | ((q3 & 0xff) << 24);
}

// fused f32->int8 convert of wq,wk,wv into one contiguous 48MB dst
__global__ __launch_bounds__(256) void wconv3_k(const float* __restrict__ a,
                                                const float* __restrict__ b,
                                                const float* __restrict__ c,
                                                int8_t* __restrict__ out) {
  const int which = blockIdx.x >> 14;
  const int sub = blockIdx.x & 16383;
  const float* src = (which == 0) ? a : (which == 1) ? b : c;
  const int idx = sub * 256 + threadIdx.x;
  const float4 v = ((const float4*)src)[idx];  // int4-valued floats, exact
  const int q0 = __float2int_rn(v.x), q1 = __float2int_rn(v.y);
  const int q2 = __float2int_rn(v.z), q3 = __float2int_rn(v.w);
  ((int*)out)[(size_t)which * 4194304 + idx] =
      (q0 & 0xff) | ((q1 & 0xff) << 8) | ((q2 & 0xff) << 16) | ((q3 & 0xff) << 24);
}

__global__ __launch_bounds__(256) void wconv_k(const float* __restrict__ in,
                                               int8_t* __restrict__ out) {
  const int idx = blockIdx.x * 256 + threadIdx.x;
  const float4 v = ((const float4*)in)[idx];
  const int q0 = __float2int_rn(v.x), q1 = __float2int_rn(v.y);
  const int q2 = __float2int_rn(v.z), q3 = __float2int_rn(v.w);
  ((int*)out)[idx] = (q0 & 0xff) | ((q1 & 0xff) << 8) | ((q2 & 0xff) << 16) | ((q3 & 0xff) << 24);
}

__global__ __launch_bounds__(256) void rope_tab_k(const int* __restrict__ pos,
                                                  float* __restrict__ ct,
                                                  float* __restrict__ st) {
  const int idx = blockIdx.x * 256 + threadIdx.x;  // [S][64]
  const int s = idx >> 6, j = idx & 63;
  const float inv = exp2f((float)j * -0.20762050593046016f);  // 10000^(-j/64)
  const float a = (float)pos[s] * inv;
  float si, c;
  sincosf(a, &si, &c);
  ct[idx] = c;
  st[idx] = si;
}

// ---------------------------------------------------------------------------
// int8 MFMA GEMM — exact R6/R8 structure (best measured: 116 µs, 37%
// MfmaUtil). R7/R9/R10/R11 variants (A-in-reg, 256x256, 2 blocks/CU,
// 8-phase) all null or regress; this is the accepted plateau.
// ---------------------------------------------------------------------------
template <int MODE>
__device__ __forceinline__ void gemm_body(
    int8_t* __restrict__ LS, const int8_t* __restrict__ A8,
    const int8_t* __restrict__ W8, const float* __restrict__ s0,
    const float* __restrict__ s1, const float* __restrict__ s2,
    const float* __restrict__ ctab, const float* __restrict__ stab,
    void* __restrict__ out0, void* __restrict__ out1, void* __restrict__ out2,
    int nwg) {
  int8_t* const Abase = LS;            // 3 x 16KB (128 rows x 128B)
  int8_t* const Bbase = LS + 49152;    // 3 x 32KB (256 rows x 128B)

  const int t = threadIdx.x;
  const int w = t >> 6, lane = t & 63, g = lane >> 4, l15 = lane & 15;
  const int wm = w >> 2, wn = w & 3;  // 2 x 4 wave grid

  // XCD-contiguous logical id, then 4x4 tile-group swizzle for L2 locality
  const int bid = blockIdx.x;
  const int lb = (bid & 7) * (nwg >> 3) + (bid >> 3);
  const int within = lb & 15, g16 = lb >> 4;
  const int bm = ((g16 & 3) * 4 + (within >> 2)) * 128;
  const int bn = ((g16 >> 2) * 4 + (within & 3)) * 256;

  // ---- staging descriptors (XOR chunk swizzle, proven 0-conflict) ----
  const int rowo = lane >> 3;
  const int schunk = ((lane & 7) ^ rowo) * 16;
  const int8_t* srcA[2];
  const int8_t* srcB[4];
#pragma unroll
  for (int i = 0; i < 2; ++i)
    srcA[i] = A8 + (size_t)(bm + w * 16 + i * 8 + rowo) * D_DIM + schunk;
#pragma unroll
  for (int i = 0; i < 4; ++i)
    srcB[i] = W8 + (size_t)(bn + w * 32 + i * 8 + rowo) * D_DIM + schunk;

#define STAGE(KT, BI)                                                       \
  {                                                                         \
    const int kof_ = (KT) * 128;                                            \
    int8_t* Ad_ = Abase + (BI) * 16384 + w * 2048;                          \
    int8_t* Bd_ = Bbase + (BI) * 32768 + w * 4096;                          \
    _Pragma("unroll") for (int i_ = 0; i_ < 2; ++i_)                        \
        gl_lds16(srcA[i_] + kof_, Ad_ + i_ * 1024);                         \
    _Pragma("unroll") for (int i_ = 0; i_ < 4; ++i_)                        \
        gl_lds16(srcB[i_] + kof_, Bd_ + i_ * 1024);                         \
  }

  // per-wave n-column base; frag ni and ni+2 are the (d, d+64) RoPE pair
  const int nc0 = (wn & 1) * 32 + (wn >> 1) * 128;

  // ---- fragment read offsets ----
  const int coff0 = (g ^ (l15 & 7)) * 16;
  const int coff1 = ((4 | g) ^ (l15 & 7)) * 16;
  const int aoff = (wm * 64 + l15) * 128;  // + mi*2048
  int boff[4];
#pragma unroll
  for (int ni = 0; ni < 4; ++ni)
    boff[ni] = (nc0 + (ni & 1) * 16 + (ni >> 1) * 64 + l15) * 128;

  v4i fa[4], fb[4];  // kk=0 frag set (read-ahead across the barrier)
  v4i ga[4], gb[4];  // kk=1 frag set (read within the step)

#define RD(FA, FB, BI, COFF)                                                \
  {                                                                         \
    const int8_t* Ab_ = Abase + (BI) * 16384;                               \
    const int8_t* Bb_ = Bbase + (BI) * 32768;                               \
    _Pragma("unroll") for (int mi_ = 0; mi_ < 4; ++mi_)                     \
        FA[mi_] = *(const v4i*)(Ab_ + aoff + mi_ * 2048 + (COFF));          \
    _Pragma("unroll") for (int ni_ = 0; ni_ < 4; ++ni_)                     \
        FB[ni_] = *(const v4i*)(Bb_ + boff[ni_] + (COFF));                  \
  }

#define MM(FA, FB)                                                          \
  _Pragma("unroll") for (int mi_ = 0; mi_ < 4; ++mi_)                       \
  _Pragma("unroll") for (int ni_ = 0; ni_ < 4; ++ni_)                       \
      acc[mi_][ni_] = __builtin_amdgcn_mfma_i32_16x16x64_i8(                \
          FA[mi_], FB[ni_], acc[mi_][ni_], 0, 0, 0);

  v4i acc[4][4];
#pragma unroll
  for (int mi = 0; mi < 4; ++mi)
#pragma unroll
    for (int ni = 0; ni < 4; ++ni) acc[mi][ni] = (v4i){0, 0, 0, 0};

  STAGE(0, 0)
  STAGE(1, 1)
  asm volatile("s_waitcnt vmcnt(6)" ::: "memory");  // stage(0) retired
  __builtin_amdgcn_s_barrier();
  __builtin_amdgcn_sched_barrier(0);
  RD(fa, fb, 0, coff0)

  for (int t3 = 0; t3 < 33; t3 += 3) {
#pragma unroll
    for (int u = 0; u < 3; ++u) {
      const int kt = t3 + u;
      if (kt < 32) {
        // safe pre-barrier: writes buf (u+2)%3, whose readers all finished
        // before the trailing barrier of step kt-1 (== entry to this step).
        if (kt + 2 < 32) STAGE(kt + 2, ((u + 2) % 3))
        RD(ga, gb, u, coff1)  // kk1 reads; latency hides under MM(fa,fb)
        __builtin_amdgcn_s_setprio(1);
        MM(fa, fb)
        MM(ga, gb)
        __builtin_amdgcn_s_setprio(0);
        // prove stage(kt+1) retired: outstanding is only stage(kt+2)
        if (kt + 2 < 32)
          asm volatile("s_waitcnt vmcnt(6)" ::: "memory");
        else
          asm volatile("s_waitcnt vmcnt(0)" ::: "memory");
        __builtin_amdgcn_s_barrier();
        __builtin_amdgcn_sched_barrier(0);
        if (kt + 1 < 32) RD(fa, fb, ((u + 1) % 3), coff0)  // crosses into kt+1
      }
    }
  }
#undef STAGE
#undef RD
#undef MM

  // ---- epilogue (C/D map: row = g*4+r, col = l15 within each 16x16) ----
  const int srow0 = bm + wm * 64;
  if (MODE == 1) {
    float* dst = (float*)out0;
#pragma unroll
    for (int ni = 0; ni < 4; ++ni) {
      const int col = bn + nc0 + (ni & 1) * 16 + (ni >> 1) * 64 + l15;
      const float sc = 0.1f * s0[col];
#pragma unroll
      for (int mi = 0; mi < 4; ++mi)
#pragma unroll
        for (int r = 0; r < 4; ++r)
          dst[(size_t)(srow0 + mi * 16 + g * 4 + r) * D_DIM + col] =
              (float)acc[mi][ni][r] * sc;
    }
  } else {
    const int seg = bn >> 12;        // 0=Q 1=K 2=V (BN=256 < 4096, uniform)
    const int bcol = bn & 4095;
    if (seg == 2) {
      _Float16* dst = (_Float16*)out2;
#pragma unroll
      for (int ni = 0; ni < 4; ++ni) {
        const int col = bcol + nc0 + (ni & 1) * 16 + (ni >> 1) * 64 + l15;
        const float scv = 0.1f * s2[col];
#pragma unroll
        for (int mi = 0; mi < 4; ++mi)
#pragma unroll
          for (int r = 0; r < 4; ++r) {
            const int s = srow0 + mi * 16 + g * 4 + r;
            dst[(size_t)col * S_LEN + s] = (_Float16)quant128((float)acc[mi][ni][r] * scv);
          }
      }
    } else {
      const float* wsc = seg ? s1 : s0;
      int8_t* dst = seg ? (int8_t*)out1 : (int8_t*)out0;
      const int hb = bcol + (wn >> 1) * 128;  // head base column
#pragma unroll
      for (int ni = 0; ni < 2; ++ni) {        // low-d frag; pair is ni+2
        const int dlo = (wn & 1) * 32 + ni * 16 + l15;  // 0..63 within head
        const int clo = hb + dlo;
        const float sc0 = 0.1f * wsc[clo];
        const float sc1 = 0.1f * wsc[clo + 64];
#pragma unroll
        for (int mi = 0; mi < 4; ++mi)
#pragma unroll
          for (int r = 0; r < 4; ++r) {
            const int s = srow0 + mi * 16 + g * 4 + r;
            const float c = ctab[s * 64 + dlo];
            const float si = stab[s * 64 + dlo];
            const float x1 = (float)acc[mi][ni][r] * sc0;
            const float x2 = (float)acc[mi][ni + 2][r] * sc1;
            dst[(size_t)s * D_DIM + clo] = (int8_t)quant128(x1 * c - x2 * si);
            dst[(size_t)s * D_DIM + clo + 64] = (int8_t)quant128(x2 * c + x1 * si);
          }
      }
    }
  }
}

__global__ __launch_bounds__(512) void gemm_qkv(
    const int8_t* __restrict__ A8, const int8_t* __restrict__ W8,
    const float* __restrict__ s0, const float* __restrict__ s1,
    const float* __restrict__ s2, const float* __restrict__ ctab,
    const float* __restrict__ stab, void* __restrict__ out0,
    void* __restrict__ out1, void* __restrict__ out2) {
  __shared__ __align__(16) int8_t LS[3 * 16384 + 3 * 32768];  // 144 KB
  gemm_body<0>(LS, A8, W8, s0, s1, s2, ctab, stab, out0, out1, out2, 768);
}

__global__ __launch_bounds__(512) void gemm_out(
    const int8_t* __restrict__ A8, const int8_t* __restrict__ W8,
    const float* __restrict__ s0, const float* __restrict__ ctab,
    const float* __restrict__ stab, void* __restrict__ out0) {
  __shared__ __align__(16) int8_t LS[3 * 16384 + 3 * 32768];  // 144 KB
  gemm_body<1>(LS, A8, W8, s0, s0, s0, ctab, stab, out0, out0, out0, 256);
}

// ---------------------------------------------------------------------------
// Flash attention v9 = v8 body + CAUSAL LOAD BALANCING.
// v8: block x had jj = 15-x, work T = 2jj+2 tiles (2..32, mean 17). With
// 512 blocks at 2/CU and linear dispatch id x+16*y, the co-resident pair on
// a CU is (id, id+256) = same x, same jj — so some CUs carry 2x32 tile-units
// while others carry 2x2; duration is set by the 32-unit CUs (~1.9x balanced).
// Fix: jj = (h<16) ? 15-x : x. Pair (x,y)/(x,y+16) then has jj-sum 15 ->
// uniform 34 tile-units per CU. Bijective over (jj,h); work total, masking,
// staging, numerics unchanged — placement heuristic only (null if wrong,
// never incorrect).
// ---------------------------------------------------------------------------
__global__ __launch_bounds__(512, 4) void attn_v9(
    const int8_t* __restrict__ q8, const int8_t* __restrict__ k8,
    const _Float16* __restrict__ vT, int8_t* __restrict__ o8) {
  __shared__ __align__(16) int8_t Kls[3][8192];   // 64 slots x 128 B (d)
  __shared__ __align__(16) int8_t Vls[3][16384];  // 128 d x 128 B (64 keys f16)
  const int h = blockIdx.y;
  const int jj = (h < 16) ? (15 - blockIdx.x) : blockIdx.x;  // pair-balanced
  const int t = threadIdx.x;
  const int w = t >> 6, lane = t & 63, g = lane >> 4, l15 = lane & 15;
  const int T = 2 * jj + 2;            // shared key-tile count (8 waves)
  const int q0 = (jj * 8 + w) * 16;    // wave-private q-tile
  const int q_lane = q0 + l15;         // this lane's q-row (score column)
  const float SSCALE = 8.838834764831845e-4f;  // 0.01 / sqrt(128)
  const v8h vones = {(_Float16)1, (_Float16)1, (_Float16)1, (_Float16)1,
                     (_Float16)1, (_Float16)1, (_Float16)1, (_Float16)1};

  // --- per-thread DMA descriptors (512 threads: K = 1 instr, V = 2) ---
  const int ks_slot = t >> 3;
  const int ks_cs = (t & 7) ^ (ks_slot & 7);  // XOR bank swizzle via source
  const int ks_key = ((ks_slot >> 5) & 1) * 32 + ((ks_slot >> 3) & 1) * 16 +
                     ((ks_slot >> 2) & 1) * 8 + ((ks_slot >> 4) & 1) * 4 +
                     (ks_slot & 3);  // slot -> key bit permutation (v5-proven)
  const int k_src = ks_key * D_DIM + ks_cs * 16;  // bytes within K tile
  const int k_dst = t * 16;
  int v_src[2], v_dst[2];
#pragma unroll
  for (int i = 0; i < 2; ++i) {
    const int lin = i * 512 + t;
    const int d = lin >> 3;
    const int cs = (lin & 7) ^ (d & 7);
    v_src[i] = d * S_LEN + cs * 8;  // f16 units; V keys in natural order
    v_dst[i] = lin * 16;
  }
  const int8_t* kbg = k8 + (size_t)h * HDIM;
  const _Float16* vbg = vT + (size_t)h * HDIM * S_LEN;

  auto stage = [&](int kt, int b) {
    const int8_t* ks = kbg + (size_t)kt * (64 * D_DIM);
    const _Float16* vs = vbg + kt * 64;
    gl_lds16(ks + k_src, &Kls[b][k_dst]);
#pragma unroll
    for (int i = 0; i < 2; ++i) gl_lds16(vs + v_src[i], &Vls[b][v_dst[i]]);
  };

  // Q fragments (B-operand of swapped QK): rows q0..q0+15
  const v4i qa0 = *(const v4i*)(q8 + (size_t)q_lane * D_DIM + h * HDIM + g * 16);
  const v4i qa1 = *(const v4i*)(q8 + (size_t)q_lane * D_DIM + h * HDIM + 64 + g * 16);

  v4f o[8];
#pragma unroll
  for (int n = 0; n < 8; ++n) o[n] = (v4f){0.f, 0.f, 0.f, 0.f};
  v4f lacc = (v4f){0.f, 0.f, 0.f, 0.f};  // denom per o-row (q = g*4+r)
  float m_i = -INFINITY;                 // running max for q = q_lane

  stage(0, 0);
  if (T > 1) stage(1, 1);

  int bi = 0;
  for (int kt = 0; kt < T; ++kt) {
    if (kt + 1 < T)
      asm volatile("s_waitcnt vmcnt(3)" ::: "memory");  // stage(kt) retired
    else
      asm volatile("s_waitcnt vmcnt(0)" ::: "memory");  // last tile
    __builtin_amdgcn_s_barrier();
    __builtin_amdgcn_sched_barrier(0);  // fence: nothing hoists above barrier
    if (kt + 2 < T) stage(kt + 2, bi >= 1 ? bi - 1 : bi + 2);  // (bi+2)%3

    // ---- scores: swapped int8 MFMA; slot s = nt*16 + g*4 + r, col = q ----
    const int ksw = (l15 & 7);
    float sc[4][4];
#pragma unroll
    for (int nt = 0; nt < 4; ++nt) {
      const int8_t* kr = &Kls[bi][(nt * 16 + l15) * 128];
      const v4i kb0 = *(const v4i*)(kr + ((g ^ ksw) * 16));
      const v4i kb1 = *(const v4i*)(kr + (((4 + g) ^ ksw) * 16));
      v4i c = (v4i){0, 0, 0, 0};
      c = __builtin_amdgcn_mfma_i32_16x16x64_i8(kb0, qa0, c, 0, 0, 0);
      c = __builtin_amdgcn_mfma_i32_16x16x64_i8(kb1, qa1, c, 0, 0, 0);
#pragma unroll
      for (int r = 0; r < 4; ++r) {
        float s = (float)c[r] * SSCALE;
        if (kt >= T - 2) {  // diagonal spans the last TWO tiles (128 q rows)
          const int key = kt * 64 + ((nt >> 1) << 5) + ((g >> 1) << 4) +
                          ((g & 1) << 3) + ((nt & 1) << 2) + r;
          if (key > q_lane) s = -1.0e30f;
        }
        sc[nt][r] = s;
      }
    }
    // ---- online softmax: per-lane column max + 2 shfl_xor across g ----
    float mx = fmaxf(fmaxf(fmaxf(sc[0][0], sc[0][1]), fmaxf(sc[0][2], sc[0][3])),
                     fmaxf(fmaxf(sc[1][0], sc[1][1]), fmaxf(sc[1][2], sc[1][3])));
    mx = fmaxf(mx, fmaxf(fmaxf(fmaxf(sc[2][0], sc[2][1]), fmaxf(sc[2][2], sc[2][3])),
                         fmaxf(fmaxf(sc[3][0], sc[3][1]), fmaxf(sc[3][2], sc[3][3]))));
    mx = fmaxf(mx, __shfl_xor(mx, 16));
    mx = fmaxf(mx, __shfl_xor(mx, 32));
    const float mnew = fmaxf(m_i, mx);
    const float alpha = __expf(m_i - mnew);
    m_i = mnew;

    float p[4][4];
#pragma unroll
    for (int nt = 0; nt < 4; ++nt)
#pragma unroll
      for (int r = 0; r < 4; ++r) p[nt][r] = __expf(sc[nt][r] - m_i);

    // P -> f16 A-frags, purely in-lane (slot permutation absorbed in K rows)
    v8h ph0, ph1;
#pragma unroll
    for (int e = 0; e < 8; ++e) {
      ph0[e] = (_Float16)p[e >> 2][e & 3];
      ph1[e] = (_Float16)p[2 + (e >> 2)][e & 3];
    }
    // alpha for this lane's o-rows (q = g*4+r): fetch from lane l15 = g*4+r
    float a_r[4];
#pragma unroll
    for (int r = 0; r < 4; ++r)
      a_r[r] = __shfl(alpha, (lane & 48) | (g * 4 + r));
#pragma unroll
    for (int n = 0; n < 8; ++n)
#pragma unroll
      for (int r = 0; r < 4; ++r) o[n][r] *= a_r[r];
#pragma unroll
    for (int r = 0; r < 4; ++r) lacc[r] *= a_r[r];

    __builtin_amdgcn_s_setprio(1);
    // denominator rides the MFMA pipe (B = ones); same f16 P as numerator
    lacc = __builtin_amdgcn_mfma_f32_16x16x32_f16(ph0, vones, lacc, 0, 0, 0);
    lacc = __builtin_amdgcn_mfma_f32_16x16x32_f16(ph1, vones, lacc, 0, 0, 0);
    // ---- PV: V from LDS (natural key order), XOR-swizzled b128 reads ----
#pragma unroll
    for (int nt = 0; nt < 8; ++nt) {
      const int8_t* vr = &Vls[bi][(nt * 16 + l15) * 128];
      const v8h v0 = *(const v8h*)(vr + ((g ^ ksw) * 16));
      const v8h v1 = *(const v8h*)(vr + (((4 + g) ^ ksw) * 16));
      o[nt] = __builtin_amdgcn_mfma_f32_16x16x32_f16(ph0, v0, o[nt], 0, 0, 0);
      o[nt] = __builtin_amdgcn_mfma_f32_16x16x32_f16(ph1, v1, o[nt], 0, 0, 0);
    }
    __builtin_amdgcn_s_setprio(0);

    bi = (bi == 2) ? 0 : bi + 1;
  }

  // ---- epilogue: normalize + int8 quantize, wave-private, no barrier ----
#pragma unroll
  for (int r = 0; r < 4; ++r) {
    const float rL = 1.0f / lacc[r];
    const size_t row = (size_t)(q0 + g * 4 + r) * D_DIM + h * HDIM;
#pragma unroll
    for (int nt = 0; nt < 8; ++nt) {
      // out = res*0.1/L; out_q = rint(out/0.1) clamp +-127 (0.1 cancels)
      const int q = (int)fminf(fmaxf(rintf(o[nt][r] * rL), -127.f), 127.f);
      o8[row + nt * 16 + l15] = (int8_t)q;
    }
  }
}

// ---------------------------------------------------------------------------
extern "C" void kernel_launch(void* const* d_in, const int* in_sizes, int n_in,
                              void* d_out, int out_size, void* d_ws, size_t ws_size,
                              hipStream_t stream) {
  (void)in_sizes; (void)n_in; (void)out_size; (void)ws_size;
  const float* hidden = (const float*)d_in[0];
  const float* wq = (const float*)d_in[1];
  const float* wk = (const float*)d_in[2];
  const float* wv = (const float*)d_in[3];
  const float* wo = (const float*)d_in[4];
  const float* sq = (const float*)d_in[5];
  const float* sk = (const float*)d_in[6];
  const float* sv = (const float*)d_in[7];
  const float* so = (const float*)d_in[8];
  // d_in[9] = attention_mask (pure causal; handled analytically)
  const int* pos = (const int*)d_in[10];
  float* out = (float*)d_out;

  char* ws = (char*)d_ws;
  int8_t* h8 = (int8_t*)ws;                                   // 8 MB (later o8)
  int8_t* q8 = (int8_t*)(ws + (8ull << 20));                  // 8 MB
  int8_t* k8 = (int8_t*)(ws + (16ull << 20));                 // 8 MB
  _Float16* vT = (_Float16*)(ws + (24ull << 20));             // 16 MB f16 [D][S]
  int8_t* w8a = (int8_t*)(ws + (40ull << 20));                // 16 MB (wq, later wo)
  int8_t* w8b = (int8_t*)(ws + (56ull << 20));                // 16 MB (wk)
  int8_t* w8c = (int8_t*)(ws + (72ull << 20));                // 16 MB (wv)
  float* ctab = (float*)(ws + (88ull << 20));                 // 512 KB
  float* stab = (float*)(ws + (88ull << 20) + (512ull << 10));
  int8_t* o8 = h8;  // h8 dead after qkv-GEMM; attn writes o8 there

  hipLaunchKernelGGL(rope_tab_k, dim3(512), dim3(256), 0, stream, pos, ctab, stab);
  hipLaunchKernelGGL(quant_hidden_k, dim3(8192), dim3(256), 0, stream, hidden, h8);
  hipLaunchKernelGGL(wconv3_k, dim3(49152), dim3(256), 0, stream, wq, wk, wv, w8a);

  // fused QKV: 16 m-tiles x 48 n-tiles = 768 blocks
  hipLaunchKernelGGL(gemm_qkv, dim3(768), dim3(512), 0, stream, h8, w8a,
                     sq, sk, sv, ctab, stab, (void*)q8, (void*)k8, (void*)vT);
  hipLaunchKernelGGL(wconv_k, dim3(16384), dim3(256), 0, stream, wo, w8a);  // QKV weights dead
  // attn: 16 q-groups x 32 heads, 512 threads (8 waves), 2 blocks/CU,
  // pair-balanced jj mapping (uniform 34 tile-units per CU)
  hipLaunchKernelGGL(attn_v9, dim3(16, 32), dim3(512), 0, stream, q8, k8, vT, o8);
  // out-proj: 16 x 16 = 256 blocks
  hipLaunchKernelGGL(gemm_out, dim3(256), dim3(512), 0, stream, o8, w8a,
                     so, ctab, stab, (void*)out);
}